// Round 5
// baseline (1443.644 us; speedup 1.0000x reference)
//
#include <hip/hip_runtime.h>
#include <math.h>
#include <stdint.h>

#define TPC 225
#define NCLS 224
#define NHID 1024
#define BATCH 2048
#define CAP 256      // bucket capacity per class (mean ~9.1)
#define LSTRIDE 256  // logits ws row stride (floats)
#define NCHUNK 8     // d-chunks per row
#define CHUNK_D 128  // NHID / NCHUNK
#define SLAB_ROWS 16 // d-rows staged per slab
#define NSLAB 8      // CHUNK_D / SLAB_ROWS
#define KSP 228      // padded LDS row stride (dwords, %4==0 for b128 reads)

typedef unsigned int u32;
typedef __attribute__((address_space(1))) const u32 gbl_u32;
typedef __attribute__((address_space(3))) u32 lds_u32;

// ---------------------------------------------------------------------------
// Kernel 1: bucket examples by class. Single block, LDS atomics.
// ---------------------------------------------------------------------------
__global__ __launch_bounds__(256) void hs_bucket(const int* __restrict__ labels,
                                                 int* __restrict__ bucket,
                                                 int* __restrict__ cnt) {
    __shared__ int scnt[NCLS];
    const int t = threadIdx.x;
    for (int i = t; i < NCLS; i += 256) scnt[i] = 0;
    __syncthreads();
    for (int b = t; b < BATCH; b += 256) {
        int lab = labels[b];
        int c = lab / TPC;
        int pos = atomicAdd(&scnt[c], 1);
        bucket[c * CAP + pos] = b;
    }
    __syncthreads();
    for (int i = t; i < NCLS; i += 256) cnt[i] = scnt[i];
}

// ---------------------------------------------------------------------------
// Async staging: one 16-row slab of the W tile (KS dwords/row, contiguous in
// global) -> LDS rows padded to KSP dwords. Row-granular width-4 DMA: per row
// 4 instrs at dword offsets {0,64,128,KS-64} (overlap region double-written
// with identical data; stays in-bounds globally). Wave w stages rows w*4..+3.
// ---------------------------------------------------------------------------
template <int KS>
__device__ __forceinline__ void stage_slab(const float* __restrict__ gslab,
                                           float* __restrict__ lbuf,
                                           const int lane, const int wave) {
#pragma unroll
    for (int i = 0; i < 4; ++i) {
        const int r = wave * 4 + i;
        const float* gr = gslab + r * KS + lane;  // per-lane global src
        float* lr = lbuf + r * KSP;               // wave-uniform LDS dst
#pragma unroll
        for (int o = 0; o < 4; ++o) {
            const int off = (o < 3) ? o * 64 : (KS - 64);
            __builtin_amdgcn_global_load_lds((gbl_u32*)(gr + off),
                                             (lds_u32*)(lr + off), 4, 0, 0);
        }
    }
}

// ---------------------------------------------------------------------------
// LDS-staged chunk GEMM: RW rows x KS cols over 128 d. Lane owns k=4*lane+j
// (ds_read_b128 weights, float4 stores). m97 pipeline: stage slab s+1, compute
// slab s, __syncthreads (compiler drains vmcnt before s_barrier).
// ---------------------------------------------------------------------------
template <int RW, int KS>
__device__ __forceinline__ void gemm_tile_lds(const float* __restrict__ xb,
                                              const int* rows, const int* rval,
                                              const float* __restrict__ wtile,
                                              float* __restrict__ lds,
                                              float* __restrict__ outp,
                                              const int lane, const int wave) {
    const float* xp[RW];
#pragma unroll
    for (int rl = 0; rl < RW; rl++) xp[rl] = xb + (size_t)rows[rl] * NHID;
    float acc[RW][4];
#pragma unroll
    for (int rl = 0; rl < RW; rl++)
#pragma unroll
        for (int j = 0; j < 4; j++) acc[rl][j] = 0.f;

    stage_slab<KS>(wtile, lds, lane, wave);
    __syncthreads();
    for (int s = 0; s < NSLAB; ++s) {
        const float* buf = lds + (s & 1) * (SLAB_ROWS * KSP);
        if (s + 1 < NSLAB)
            stage_slab<KS>(wtile + (s + 1) * (SLAB_ROWS * KS),
                           lds + ((s + 1) & 1) * (SLAB_ROWS * KSP), lane, wave);
#pragma unroll
        for (int dql = 0; dql < 4; ++dql) {
            const int dq = s * 4 + dql;
            float4 xq[RW];
#pragma unroll
            for (int rl = 0; rl < RW; rl++)
                xq[rl] = *(const float4*)(xp[rl] + dq * 4);
            float4 wv[4];
#pragma unroll
            for (int di = 0; di < 4; di++)
                wv[di] = *(const float4*)&buf[(dql * 4 + di) * KSP + 4 * lane];
#pragma unroll
            for (int rl = 0; rl < RW; rl++)
#pragma unroll
                for (int di = 0; di < 4; di++) {
                    const float xv = ((const float*)&xq[rl])[di];
                    acc[rl][0] = fmaf(xv, wv[di].x, acc[rl][0]);
                    acc[rl][1] = fmaf(xv, wv[di].y, acc[rl][1]);
                    acc[rl][2] = fmaf(xv, wv[di].z, acc[rl][2]);
                    acc[rl][3] = fmaf(xv, wv[di].w, acc[rl][3]);
                }
        }
        __syncthreads();
    }
    // store: lane owns k = 4*lane..4*lane+3 (garbage lanes masked by k<KS)
    const int k0 = 4 * lane;
#pragma unroll
    for (int rl = 0; rl < RW; rl++) {
        if (!rval[rl]) continue;
        float* op = outp + (size_t)rows[rl] * LSTRIDE + k0;
        if (k0 + 3 < KS) {
            *(float4*)op = make_float4(acc[rl][0], acc[rl][1], acc[rl][2], acc[rl][3]);
        } else {
#pragma unroll
            for (int j = 0; j < 4; j++)
                if (k0 + j < KS) op[j] = acc[rl][j];
        }
    }
}

// ---------------------------------------------------------------------------
// Kernel 2: top logits. Grid = 256 row-blocks x 8 d-chunks, 256 threads =
// 4 waves = 4 row-groups of 2 rows. LDS-staged weights; partials to 8 bufs.
// ---------------------------------------------------------------------------
__global__ __launch_bounds__(256, 4) void hs_tlogits(const float* __restrict__ x,
                                                     const float* __restrict__ W,
                                                     float* __restrict__ twsP) {
    __shared__ float lds[2 * SLAB_ROWS * KSP + 32];  // ~29.3 KB -> 5 blocks/CU
    const int rb = blockIdx.x >> 3;  // row-block 0..255
    const int q = blockIdx.x & 7;    // d-chunk 0..7
    const int lane = threadIdx.x & 63;
    const int wave = threadIdx.x >> 6;
    int rows[2] = {rb * 8 + wave * 2, rb * 8 + wave * 2 + 1};
    int rval[2] = {1, 1};
    const float* wtile = W + (size_t)q * CHUNK_D * NCLS;
    gemm_tile_lds<2, NCLS>(x + q * CHUNK_D, rows, rval, wtile, lds,
                           twsP + (size_t)q * BATCH * LSTRIDE, lane, wave);
}

// ---------------------------------------------------------------------------
// Kernel 3: bottom logits. Grid = 224 classes x 8 d-chunks, 256 threads =
// 4 waves = 4 row-groups. LDS-staged weights; partials to 8 bufs.
// ---------------------------------------------------------------------------
template <int RW>
__device__ __forceinline__ void bpass_lds(const float* __restrict__ xb,
                                          const float* __restrict__ wtile,
                                          const int* __restrict__ bucket_c,
                                          const int base, const int n,
                                          float* __restrict__ lds,
                                          float* __restrict__ bp,
                                          const int lane, const int wave) {
    int rows[RW], rval[RW];
#pragma unroll
    for (int rl = 0; rl < RW; rl++) {
        int idx = base + wave * RW + rl;
        rows[rl] = bucket_c[idx < n ? idx : 0];  // pad rows alias entry 0
        rval[rl] = (idx < n);
    }
    gemm_tile_lds<RW, TPC>(xb, rows, rval, wtile, lds, bp, lane, wave);
}

__global__ __launch_bounds__(256, 4) void hs_blogits(const float* __restrict__ x,
                                                     const float* __restrict__ Wb,
                                                     const int* __restrict__ bucket,
                                                     const int* __restrict__ cnt,
                                                     float* __restrict__ bws) {
    __shared__ float lds[2 * SLAB_ROWS * KSP + 32];
    const int c = blockIdx.x >> 3;  // class
    const int q = blockIdx.x & 7;   // d-chunk
    const int n = cnt[c];
    if (n == 0) return;
    const int lane = threadIdx.x & 63;
    const int wave = threadIdx.x >> 6;  // row-group AND staging wave
    const float* wtile = Wb + (size_t)c * (NHID * TPC) + (size_t)q * CHUNK_D * TPC;
    const float* xb = x + q * CHUNK_D;
    const int* bucket_c = bucket + c * CAP;
    float* bp = bws + (size_t)q * BATCH * LSTRIDE;

    for (int base = 0; base < n; base += 16) {
        int m = n - base;
        if (m > 16) m = 16;
        const int RW = (m + 3) >> 2;
        switch (RW) {  // block-uniform
            case 1: bpass_lds<1>(xb, wtile, bucket_c, base, n, lds, bp, lane, wave); break;
            case 2: bpass_lds<2>(xb, wtile, bucket_c, base, n, lds, bp, lane, wave); break;
            case 3: bpass_lds<3>(xb, wtile, bucket_c, base, n, lds, bp, lane, wave); break;
            default: bpass_lds<4>(xb, wtile, bucket_c, base, n, lds, bp, lane, wave); break;
        }
    }
}

// ---------------------------------------------------------------------------
// Kernel 4: finish. One wave per row: sum 8 d-chunk partials, softmax over
// top (224) and bottom (225) logits (bias added here), out = p_cls * p_word.
// ---------------------------------------------------------------------------
__global__ __launch_bounds__(256) void hs_finish(const float* __restrict__ tws,
                                                 const float* __restrict__ bws,
                                                 const int* __restrict__ labels,
                                                 const float* __restrict__ b_top,
                                                 const float* __restrict__ b_bot,
                                                 float* __restrict__ out) {
    const int lane = threadIdx.x & 63;
    const int wave = threadIdx.x >> 6;
    const int row = blockIdx.x * 4 + wave;
    const int label = labels[row];
    const int c = label / TPC;
    const int word = label - c * TPC;

    float p[2];
#pragma unroll
    for (int lvl = 0; lvl < 2; lvl++) {
        const int NS = lvl ? TPC : NCLS;
        const int pick = lvl ? word : c;
        const float* lws = lvl ? bws : tws;
        const float* bias = lvl ? (b_bot + c * TPC) : b_top;
        float lg[4];
#pragma unroll
        for (int j = 0; j < 4; j++) {
            int k = lane + 64 * j;
            if (k < NS) {
                float v = 0.f;
#pragma unroll
                for (int pq = 0; pq < NCHUNK; pq++)
                    v += lws[((size_t)pq * BATCH + row) * LSTRIDE + k];
                lg[j] = v + bias[k];
            } else {
                lg[j] = -INFINITY;
            }
        }
        float m = fmaxf(fmaxf(lg[0], lg[1]), fmaxf(lg[2], lg[3]));
#pragma unroll
        for (int off = 32; off > 0; off >>= 1) m = fmaxf(m, __shfl_xor(m, off, 64));
        float s = 0.f, pp = 0.f;
#pragma unroll
        for (int j = 0; j < 4; j++) {
            int k = lane + 64 * j;
            float e = (k < NS) ? __expf(lg[j] - m) : 0.f;
            s += e;
            if (k == pick) pp = e;
        }
#pragma unroll
        for (int off = 32; off > 0; off >>= 1) {
            s += __shfl_xor(s, off, 64);
            pp += __shfl_xor(pp, off, 64);
        }
        p[lvl] = pp / s;
    }
    if (lane == 0) out[row] = p[0] * p[1];
}

// ---------------------------------------------------------------------------
extern "C" void kernel_launch(void* const* d_in, const int* in_sizes, int n_in,
                              void* d_out, int out_size, void* d_ws, size_t ws_size,
                              hipStream_t stream) {
    const float* inputs   = (const float*)d_in[0];
    const int*   labels   = (const int*)d_in[1];
    const float* W_top    = (const float*)d_in[2];
    const float* b_top    = (const float*)d_in[3];
    const float* W_bottom = (const float*)d_in[4];
    const float* b_bottom = (const float*)d_in[5];
    float* out = (float*)d_out;

    // ws: bucket[NCLS*CAP] | cnt[NCLS] | tws[8*B*LSTRIDE] | bws[8*B*LSTRIDE]
    int* bucket = (int*)d_ws;
    int* cnt    = bucket + NCLS * CAP;
    float* tws  = (float*)(cnt + NCLS);
    float* bws  = tws + (size_t)NCHUNK * BATCH * LSTRIDE;

    hs_bucket<<<1, 256, 0, stream>>>(labels, bucket, cnt);
    hs_tlogits<<<256 * NCHUNK, 256, 0, stream>>>(inputs, W_top, tws);
    hs_blogits<<<NCLS * NCHUNK, 256, 0, stream>>>(inputs, W_bottom, bucket, cnt, bws);
    hs_finish<<<BATCH / 4, 256, 0, stream>>>(tws, bws, labels, b_top, b_bottom, out);
}

// Round 6
// 534.265 us; speedup vs baseline: 2.7021x; 2.7021x over previous
//
#include <hip/hip_runtime.h>
#include <math.h>

#define TPC 225
#define NCLS 224
#define NHID 1024
#define BATCH 2048
#define CAP 256      // bucket capacity per class (mean ~9.1)
#define LSTRIDE 256  // logits ws row stride (floats)
#define NCHUNK 8     // d-chunks per row
#define CHUNK_D 128  // NHID / NCHUNK
#define NDQ 32       // CHUNK_D / 4

// ---------------------------------------------------------------------------
// Kernel 1: bucket examples by class. Single block, LDS atomics.
// ---------------------------------------------------------------------------
__global__ __launch_bounds__(256) void hs_bucket(const int* __restrict__ labels,
                                                 int* __restrict__ bucket,
                                                 int* __restrict__ cnt) {
    __shared__ int scnt[NCLS];
    const int t = threadIdx.x;
    for (int i = t; i < NCLS; i += 256) scnt[i] = 0;
    __syncthreads();
    for (int b = t; b < BATCH; b += 256) {
        int lab = labels[b];
        int c = lab / TPC;
        int pos = atomicAdd(&scnt[c], 1);
        bucket[c * CAP + pos] = b;
    }
    __syncthreads();
    for (int i = t; i < NCLS; i += 256) cnt[i] = scnt[i];
}

// ---------------------------------------------------------------------------
// 128-d chunk GEMM, VECTORIZED weight stream. Lane owns k = 4*lane+j
// (kb clamped to KS-4 at the tail; duplicate lanes compute/store identical
// values -> benign). One global_load_dwordx4 per weight row (was 4 scalar
// dwords): 16B/lane coalescing sweet spot, 4x fewer VMEM instrs in the
// latency-bound regime. d-accumulation order identical to R4 (bit-exact).
// Register double-buffer (wA/wB, xA/xB); (256,4) caps VGPR at 128 (est ~108).
// ---------------------------------------------------------------------------
#define LW(W)                                                   \
    do {                                                        \
        _Pragma("unroll") for (int di = 0; di < 4; di++)        \
            W[di] = *(const float4*)(pw + di * KS);             \
        pw += 4 * KS;                                           \
    } while (0)

#define LX(X, dq)                                               \
    do {                                                        \
        _Pragma("unroll") for (int rl = 0; rl < RW; rl++)       \
            X[rl] = *(const float4*)(xp[rl] + (dq) * 4);        \
    } while (0)

#define FM(W, X)                                                \
    do {                                                        \
        _Pragma("unroll") for (int rl = 0; rl < RW; rl++) {     \
            _Pragma("unroll") for (int di = 0; di < 4; di++) {  \
                const float xv = ((const float*)&X[rl])[di];    \
                acc[rl][0] = fmaf(xv, W[di].x, acc[rl][0]);     \
                acc[rl][1] = fmaf(xv, W[di].y, acc[rl][1]);     \
                acc[rl][2] = fmaf(xv, W[di].z, acc[rl][2]);     \
                acc[rl][3] = fmaf(xv, W[di].w, acc[rl][3]);     \
            }                                                   \
        }                                                       \
    } while (0)

template <int RW, int KS>
__device__ __forceinline__ void gemm_chunk(const float* __restrict__ xb,
                                           const int* rows,
                                           const float* __restrict__ wq,
                                           const int lane,
                                           float acc[RW][4]) {
    const float* xp[RW];
#pragma unroll
    for (int rl = 0; rl < RW; rl++) xp[rl] = xb + (size_t)rows[rl] * NHID;
    const int kb = (4 * lane <= KS - 4) ? 4 * lane : (KS - 4);
    const float* pw = wq + kb;  // row d lives at pw + d*KS (4B-aligned ok)
#pragma unroll
    for (int rl = 0; rl < RW; rl++)
#pragma unroll
        for (int j = 0; j < 4; j++) acc[rl][j] = 0.f;

    float4 wA[4], wB[4], xA[RW], xB[RW];
    LW(wA);          // rows 0..3
    LX(xA, 0);
    for (int dq = 0; dq < NDQ; dq += 2) {
        LW(wB);                      // prefetch rows of dq+1
        LX(xB, dq + 1);
        FM(wA, xA);                  // compute dq
        if (dq + 2 < NDQ) {
            LW(wA);                  // prefetch rows of dq+2
            LX(xA, dq + 2);
        }
        FM(wB, xB);                  // compute dq+1
    }
}

template <int RW, int KS>
__device__ __forceinline__ void store_rows(float* __restrict__ outp,
                                           const int* rows, const int* rval,
                                           const float acc[RW][4],
                                           const int lane) {
    const int kb = (4 * lane <= KS - 4) ? 4 * lane : (KS - 4);
    if (4 * lane < KS) {  // overlap lanes write identical values (benign)
#pragma unroll
        for (int rl = 0; rl < RW; rl++) {
            if (!rval[rl]) continue;
            *(float4*)(outp + (size_t)rows[rl] * LSTRIDE + kb) =
                make_float4(acc[rl][0], acc[rl][1], acc[rl][2], acc[rl][3]);
        }
    }
}

// ---------------------------------------------------------------------------
// Kernel 2: top logits. Grid = 256 row-blocks x 8 d-chunks = 2048 blocks,
// 256 threads = 4 waves = 4 row-groups of 2 rows. Barrier-free; 8 partial
// buffers summed in hs_finish. NOTE: min-waves 7/8 in launch_bounds forces
// the <=64-VGPR bin and catastrophic scratch spill (R3); keep (256,4).
// ---------------------------------------------------------------------------
__global__ __launch_bounds__(256, 4) void hs_tlogits(const float* __restrict__ x,
                                                     const float* __restrict__ W,
                                                     float* __restrict__ twsP) {
    const int rb = blockIdx.x >> 3;  // row-block 0..255
    const int q = blockIdx.x & 7;    // d-chunk 0..7
    const int lane = threadIdx.x & 63;
    const int wr = threadIdx.x >> 6;  // row-group 0..3
    int rows[2] = {rb * 8 + wr * 2, rb * 8 + wr * 2 + 1};
    int rval[2] = {1, 1};
    const float* xb = x + q * CHUNK_D;
    const float* wq = W + (size_t)q * CHUNK_D * NCLS;
    float acc[2][4];
    gemm_chunk<2, NCLS>(xb, rows, wq, lane, acc);
    store_rows<2, NCLS>(twsP + (size_t)q * BATCH * LSTRIDE, rows, rval, acc, lane);
}

// ---------------------------------------------------------------------------
// Kernel 3: bottom logits. Grid = 224 classes x 8 d-chunks = 1792 blocks,
// 256 threads = 4 waves = 4 row-groups. Barrier-free; 8 partial buffers.
// ---------------------------------------------------------------------------
template <int RW>
__device__ __forceinline__ void bchunk(const float* __restrict__ xb,
                                       const float* __restrict__ wq,
                                       const int* __restrict__ bucket_c,
                                       const int base, const int n,
                                       const int lane, const int wr,
                                       float* __restrict__ bp) {
    int rows[RW], rval[RW];
#pragma unroll
    for (int rl = 0; rl < RW; rl++) {
        int idx = base + wr * RW + rl;
        rows[rl] = bucket_c[idx < n ? idx : 0];  // pad rows alias entry 0
        rval[rl] = (idx < n);
    }
    float acc[RW][4];
    gemm_chunk<RW, TPC>(xb, rows, wq, lane, acc);
    store_rows<RW, TPC>(bp, rows, rval, acc, lane);
}

__global__ __launch_bounds__(256, 4) void hs_blogits(const float* __restrict__ x,
                                                     const float* __restrict__ Wb,
                                                     const int* __restrict__ bucket,
                                                     const int* __restrict__ cnt,
                                                     float* __restrict__ bws) {
    const int c = blockIdx.x >> 3;  // class
    const int q = blockIdx.x & 7;   // d-chunk
    const int n = cnt[c];
    if (n == 0) return;
    const int lane = threadIdx.x & 63;
    const int wr = threadIdx.x >> 6;  // row-group 0..3
    const float* wq = Wb + (size_t)c * (NHID * TPC) + (size_t)q * CHUNK_D * TPC;
    const float* xb = x + q * CHUNK_D;
    const int* bucket_c = bucket + c * CAP;
    float* bp = bws + (size_t)q * BATCH * LSTRIDE;

    for (int base = 0; base < n; base += 16) {
        int m = n - base;
        if (m > 16) m = 16;
        const int RW = (m + 3) >> 2;
        switch (RW) {  // block-uniform
            case 1: bchunk<1>(xb, wq, bucket_c, base, n, lane, wr, bp); break;
            case 2: bchunk<2>(xb, wq, bucket_c, base, n, lane, wr, bp); break;
            case 3: bchunk<3>(xb, wq, bucket_c, base, n, lane, wr, bp); break;
            default: bchunk<4>(xb, wq, bucket_c, base, n, lane, wr, bp); break;
        }
    }
}

// ---------------------------------------------------------------------------
// Kernel 4: finish. One wave per row: sum 8 d-chunk partials, softmax over
// top (224) and bottom (225) logits (bias added here), out = p_cls * p_word.
// ---------------------------------------------------------------------------
__global__ __launch_bounds__(256) void hs_finish(const float* __restrict__ tws,
                                                 const float* __restrict__ bws,
                                                 const int* __restrict__ labels,
                                                 const float* __restrict__ b_top,
                                                 const float* __restrict__ b_bot,
                                                 float* __restrict__ out) {
    const int lane = threadIdx.x & 63;
    const int wave = threadIdx.x >> 6;
    const int row = blockIdx.x * 4 + wave;
    const int label = labels[row];
    const int c = label / TPC;
    const int word = label - c * TPC;

    float p[2];
#pragma unroll
    for (int lvl = 0; lvl < 2; lvl++) {
        const int NS = lvl ? TPC : NCLS;
        const int pick = lvl ? word : c;
        const float* lws = lvl ? bws : tws;
        const float* bias = lvl ? (b_bot + c * TPC) : b_top;
        float lg[4];
#pragma unroll
        for (int j = 0; j < 4; j++) {
            int k = lane + 64 * j;
            if (k < NS) {
                float v = 0.f;
#pragma unroll
                for (int pq = 0; pq < NCHUNK; pq++)
                    v += lws[((size_t)pq * BATCH + row) * LSTRIDE + k];
                lg[j] = v + bias[k];
            } else {
                lg[j] = -INFINITY;
            }
        }
        float m = fmaxf(fmaxf(lg[0], lg[1]), fmaxf(lg[2], lg[3]));
#pragma unroll
        for (int off = 32; off > 0; off >>= 1) m = fmaxf(m, __shfl_xor(m, off, 64));
        float s = 0.f, pp = 0.f;
#pragma unroll
        for (int j = 0; j < 4; j++) {
            int k = lane + 64 * j;
            float e = (k < NS) ? __expf(lg[j] - m) : 0.f;
            s += e;
            if (k == pick) pp = e;
        }
#pragma unroll
        for (int off = 32; off > 0; off >>= 1) {
            s += __shfl_xor(s, off, 64);
            pp += __shfl_xor(pp, off, 64);
        }
        p[lvl] = pp / s;
    }
    if (lane == 0) out[row] = p[0] * p[1];
}

// ---------------------------------------------------------------------------
extern "C" void kernel_launch(void* const* d_in, const int* in_sizes, int n_in,
                              void* d_out, int out_size, void* d_ws, size_t ws_size,
                              hipStream_t stream) {
    const float* inputs   = (const float*)d_in[0];
    const int*   labels   = (const int*)d_in[1];
    const float* W_top    = (const float*)d_in[2];
    const float* b_top    = (const float*)d_in[3];
    const float* W_bottom = (const float*)d_in[4];
    const float* b_bottom = (const float*)d_in[5];
    float* out = (float*)d_out;

    // ws: bucket[NCLS*CAP] | cnt[NCLS] | tws[8*B*LSTRIDE] | bws[8*B*LSTRIDE]
    int* bucket = (int*)d_ws;
    int* cnt    = bucket + NCLS * CAP;
    float* tws  = (float*)(cnt + NCLS);
    float* bws  = tws + (size_t)NCHUNK * BATCH * LSTRIDE;

    hs_bucket<<<1, 256, 0, stream>>>(labels, bucket, cnt);
    hs_tlogits<<<256 * NCHUNK, 256, 0, stream>>>(inputs, W_top, tws);
    hs_blogits<<<NCLS * NCHUNK, 256, 0, stream>>>(inputs, W_bottom, bucket, cnt, bws);
    hs_finish<<<BATCH / 4, 256, 0, stream>>>(tws, bws, labels, b_top, b_bottom, out);
}

// Round 7
// 431.023 us; speedup vs baseline: 3.3493x; 1.2395x over previous
//
#include <hip/hip_runtime.h>
#include <math.h>

#define TPC 225
#define NCLS 224
#define NHID 1024
#define BATCH 2048
#define CAP 256      // bucket capacity per class (mean ~9.1)
#define LSTRIDE 256  // logits ws row stride (floats)
#define NCHUNK 8     // d-chunks per row
#define CHUNK_D 128  // NHID / NCHUNK
#define NDQ 32       // CHUNK_D / 4

// ---------------------------------------------------------------------------
// Kernel 1: bucket examples by class. Single block, LDS atomics.
// ---------------------------------------------------------------------------
__global__ __launch_bounds__(256) void hs_bucket(const int* __restrict__ labels,
                                                 int* __restrict__ bucket,
                                                 int* __restrict__ cnt) {
    __shared__ int scnt[NCLS];
    const int t = threadIdx.x;
    for (int i = t; i < NCLS; i += 256) scnt[i] = 0;
    __syncthreads();
    for (int b = t; b < BATCH; b += 256) {
        int lab = labels[b];
        int c = lab / TPC;
        int pos = atomicAdd(&scnt[c], 1);
        bucket[c * CAP + pos] = b;
    }
    __syncthreads();
    for (int i = t; i < NCLS; i += 256) cnt[i] = scnt[i];
}

// ---------------------------------------------------------------------------
// Generic 128-d chunk GEMM: RW rows x KS cols, k = lane + 64j (j<4, clamped).
// EXACT R4 inner body — the ONLY variant proven spill-free at this
// toolchain's hard 64-VGPR ceiling (R2/R4/R6 all allocate exactly 64;
// anything needing more spills catastrophically, see R3/R5/R6 WRITE_SIZE).
// ---------------------------------------------------------------------------
#define LOADW(W)                                              \
    do {                                                      \
        _Pragma("unroll") for (int di = 0; di < 4; di++)      \
            _Pragma("unroll") for (int j = 0; j < 4; j++)     \
                W[di][j] = pj[j][di * KS];                    \
        _Pragma("unroll") for (int j = 0; j < 4; j++)         \
            pj[j] += 4 * KS;                                  \
    } while (0)

#define LOADX(X, dq)                                          \
    do {                                                      \
        _Pragma("unroll") for (int rl = 0; rl < RW; rl++)     \
            X[rl] = *(const float4*)(xp[rl] + (dq) * 4);      \
    } while (0)

#define FMAS(W, X)                                            \
    do {                                                      \
        _Pragma("unroll") for (int rl = 0; rl < RW; rl++) {   \
            _Pragma("unroll") for (int di = 0; di < 4; di++) {\
                float xv = ((const float*)&X[rl])[di];        \
                _Pragma("unroll") for (int j = 0; j < 4; j++) \
                    acc[rl][j] = fmaf(xv, W[di][j], acc[rl][j]); \
            }                                                 \
        }                                                     \
    } while (0)

template <int RW, int KS>
__device__ __forceinline__ void gemm_chunk(const float* __restrict__ xb,
                                           const int* rows,
                                           const float* __restrict__ wq,
                                           const int lane,
                                           float acc[RW][4]) {
    const float* xp[RW];
#pragma unroll
    for (int rl = 0; rl < RW; rl++) xp[rl] = xb + (size_t)rows[rl] * NHID;
    const float* pj[4];
#pragma unroll
    for (int j = 0; j < 4; j++) {
        int k = 64 * j + lane;
        pj[j] = wq + (k < KS ? k : KS - 1);
    }
#pragma unroll
    for (int rl = 0; rl < RW; rl++)
#pragma unroll
        for (int j = 0; j < 4; j++) acc[rl][j] = 0.f;

    float wA[4][4], wB[4][4];
    float4 xA[RW], xB[RW];
    LOADW(wA);
    LOADX(xA, 0);
    for (int dq = 0; dq < NDQ; dq += 2) {
        LOADW(wB);                  // prefetch dq+1 weights
        LOADX(xB, dq + 1);
        FMAS(wA, xA);               // compute dq
        if (dq + 2 < NDQ) {
            LOADW(wA);              // prefetch dq+2
            LOADX(xA, dq + 2);
        }
        FMAS(wB, xB);               // compute dq+1
    }
}

// ---------------------------------------------------------------------------
// Kernel 2: top logits — now structurally IDENTICAL to the proven blogits
// shape: RW=4 rows/wave (R4 A/B: RW=4 is 2x faster per MAC than RW=2 in
// this latency-bound regime). Grid = 128 row-blocks (16 rows each) x 8
// d-chunks = 1024 blocks. Barrier-free; 8 partial buffers summed in finish.
// ---------------------------------------------------------------------------
__global__ __launch_bounds__(256, 4) void hs_tlogits(const float* __restrict__ x,
                                                     const float* __restrict__ W,
                                                     float* __restrict__ twsP) {
    const int rb = blockIdx.x >> 3;  // row-block 0..127
    const int q = blockIdx.x & 7;    // d-chunk 0..7
    const int lane = threadIdx.x & 63;
    const int wr = threadIdx.x >> 6;  // row-group 0..3
    int rows[4];
#pragma unroll
    for (int rl = 0; rl < 4; rl++) rows[rl] = rb * 16 + wr * 4 + rl;
    const float* xb = x + q * CHUNK_D;
    const float* wq = W + (size_t)q * CHUNK_D * NCLS;
    float acc[4][4];
    gemm_chunk<4, NCLS>(xb, rows, wq, lane, acc);
    float* tp = twsP + (size_t)q * BATCH * LSTRIDE;
#pragma unroll
    for (int rl = 0; rl < 4; rl++)
#pragma unroll
        for (int j = 0; j < 4; j++) {
            int k = 64 * j + lane;
            if (k < NCLS) tp[(size_t)rows[rl] * LSTRIDE + k] = acc[rl][j];
        }
}

// ---------------------------------------------------------------------------
// Kernel 3: bottom logits — byte-identical to R4 (proven 132 us, 64 VGPR,
// no spill). Grid = 224 classes x 8 d-chunks, 4 waves = 4 row-groups.
// ---------------------------------------------------------------------------
template <int RW>
__device__ __forceinline__ void bchunk(const float* __restrict__ xb,
                                       const float* __restrict__ wq,
                                       const int* __restrict__ bucket_c,
                                       const int base, const int n,
                                       const int lane, const int wr,
                                       float* __restrict__ bp) {
    int rows[RW], rval[RW];
#pragma unroll
    for (int rl = 0; rl < RW; rl++) {
        int idx = base + wr * RW + rl;
        rows[rl] = bucket_c[idx < n ? idx : 0];  // pad rows alias entry 0
        rval[rl] = (idx < n);
    }
    float acc[RW][4];
    gemm_chunk<RW, TPC>(xb, rows, wq, lane, acc);
#pragma unroll
    for (int rl = 0; rl < RW; rl++) {
        if (rval[rl]) {
#pragma unroll
            for (int j = 0; j < 4; j++) {
                int k = 64 * j + lane;
                if (k < TPC) bp[(size_t)rows[rl] * LSTRIDE + k] = acc[rl][j];
            }
        }
    }
}

__global__ __launch_bounds__(256, 4) void hs_blogits(const float* __restrict__ x,
                                                     const float* __restrict__ Wb,
                                                     const int* __restrict__ bucket,
                                                     const int* __restrict__ cnt,
                                                     float* __restrict__ bws) {
    const int c = blockIdx.x >> 3;  // class
    const int q = blockIdx.x & 7;   // d-chunk
    const int n = cnt[c];
    if (n == 0) return;
    const int lane = threadIdx.x & 63;
    const int wr = threadIdx.x >> 6;  // row-group 0..3
    const float* wq = Wb + (size_t)c * (NHID * TPC) + (size_t)q * CHUNK_D * TPC;
    const float* xb = x + q * CHUNK_D;
    const int* bucket_c = bucket + c * CAP;
    float* bp = bws + (size_t)q * BATCH * LSTRIDE;

    for (int base = 0; base < n; base += 16) {
        int m = n - base;
        if (m > 16) m = 16;
        const int RW = (m + 3) >> 2;
        switch (RW) {  // block-uniform
            case 1: bchunk<1>(xb, wq, bucket_c, base, n, lane, wr, bp); break;
            case 2: bchunk<2>(xb, wq, bucket_c, base, n, lane, wr, bp); break;
            case 3: bchunk<3>(xb, wq, bucket_c, base, n, lane, wr, bp); break;
            default: bchunk<4>(xb, wq, bucket_c, base, n, lane, wr, bp); break;
        }
    }
}

// ---------------------------------------------------------------------------
// Kernel 4: finish. One wave per row: sum 8 d-chunk partials, softmax over
// top (224) and bottom (225) logits (bias added here), out = p_cls * p_word.
// ---------------------------------------------------------------------------
__global__ __launch_bounds__(256) void hs_finish(const float* __restrict__ tws,
                                                 const float* __restrict__ bws,
                                                 const int* __restrict__ labels,
                                                 const float* __restrict__ b_top,
                                                 const float* __restrict__ b_bot,
                                                 float* __restrict__ out) {
    const int lane = threadIdx.x & 63;
    const int wave = threadIdx.x >> 6;
    const int row = blockIdx.x * 4 + wave;
    const int label = labels[row];
    const int c = label / TPC;
    const int word = label - c * TPC;

    float p[2];
#pragma unroll
    for (int lvl = 0; lvl < 2; lvl++) {
        const int NS = lvl ? TPC : NCLS;
        const int pick = lvl ? word : c;
        const float* lws = lvl ? bws : tws;
        const float* bias = lvl ? (b_bot + c * TPC) : b_top;
        float lg[4];
#pragma unroll
        for (int j = 0; j < 4; j++) {
            int k = lane + 64 * j;
            if (k < NS) {
                float v = 0.f;
#pragma unroll
                for (int pq = 0; pq < NCHUNK; pq++)
                    v += lws[((size_t)pq * BATCH + row) * LSTRIDE + k];
                lg[j] = v + bias[k];
            } else {
                lg[j] = -INFINITY;
            }
        }
        float m = fmaxf(fmaxf(lg[0], lg[1]), fmaxf(lg[2], lg[3]));
#pragma unroll
        for (int off = 32; off > 0; off >>= 1) m = fmaxf(m, __shfl_xor(m, off, 64));
        float s = 0.f, pp = 0.f;
#pragma unroll
        for (int j = 0; j < 4; j++) {
            int k = lane + 64 * j;
            float e = (k < NS) ? __expf(lg[j] - m) : 0.f;
            s += e;
            if (k == pick) pp = e;
        }
#pragma unroll
        for (int off = 32; off > 0; off >>= 1) {
            s += __shfl_xor(s, off, 64);
            pp += __shfl_xor(pp, off, 64);
        }
        p[lvl] = pp / s;
    }
    if (lane == 0) out[row] = p[0] * p[1];
}

// ---------------------------------------------------------------------------
extern "C" void kernel_launch(void* const* d_in, const int* in_sizes, int n_in,
                              void* d_out, int out_size, void* d_ws, size_t ws_size,
                              hipStream_t stream) {
    const float* inputs   = (const float*)d_in[0];
    const int*   labels   = (const int*)d_in[1];
    const float* W_top    = (const float*)d_in[2];
    const float* b_top    = (const float*)d_in[3];
    const float* W_bottom = (const float*)d_in[4];
    const float* b_bottom = (const float*)d_in[5];
    float* out = (float*)d_out;

    // ws: bucket[NCLS*CAP] | cnt[NCLS] | tws[8*B*LSTRIDE] | bws[8*B*LSTRIDE]
    int* bucket = (int*)d_ws;
    int* cnt    = bucket + NCLS * CAP;
    float* tws  = (float*)(cnt + NCLS);
    float* bws  = tws + (size_t)NCHUNK * BATCH * LSTRIDE;

    hs_bucket<<<1, 256, 0, stream>>>(labels, bucket, cnt);
    hs_tlogits<<<128 * NCHUNK, 256, 0, stream>>>(inputs, W_top, tws);
    hs_blogits<<<NCLS * NCHUNK, 256, 0, stream>>>(inputs, W_bottom, bucket, cnt, bws);
    hs_finish<<<BATCH / 4, 256, 0, stream>>>(tws, bws, labels, b_top, b_bottom, out);
}